// Round 11
// baseline (500.311 us; speedup 1.0000x reference)
//
#include <hip/hip_runtime.h>
#include <cstdint>
#include <cstddef>

#define NN 8192
#define FIN 256
#define FOUT 128
#define SLOPE 0.2f
#define SHIFT 8.0f

typedef float f32x4 __attribute__((ext_vector_type(4)));
typedef __bf16 bf16x8 __attribute__((ext_vector_type(8)));
typedef int i32x4 __attribute__((ext_vector_type(4)));
typedef unsigned int u32x4 __attribute__((ext_vector_type(4)));
typedef unsigned int u32x2 __attribute__((ext_vector_type(2)));

__device__ __forceinline__ unsigned short f2bf(float f) {
  return __builtin_bit_cast(unsigned short, (__bf16)f);
}
__device__ __forceinline__ float bf2f(unsigned short u) {
  return (float)__builtin_bit_cast(__bf16, u);
}

// async global->LDS DMA, 16 B/lane; LDS dest = wave-uniform base + lane*16
__device__ __forceinline__ void async_cp16(void* lds, const void* g) {
  __builtin_amdgcn_global_load_lds(
      (const __attribute__((address_space(1))) void*)g,
      (__attribute__((address_space(3))) void*)lds, 16, 0, 0);
}

// ---------------------------------------------------------------------------
// Kernel A: h = x @ W (fp32 acc) -> ht[FOUT][NN] bf16 (transposed), plus fused
// s-reductions and the exp-factor tables:
//   Etab[2row,2row+1] = (E, E2) = (e^{s1-c}, e^{0.2 s1 - c}),
//     c = leakyrelu(s1 + SHIFT)  (>= row max of leakyrelu(s1+s2))
//   FbfF[j] = bf16(e^{s2_j}),  FbfF2[j] = bf16(e^{0.2 s2_j})   (two planes)
// so exp(leakyrelu(s1+s2) - c) = max(E*F, E2*F2)  (exp monotone, exact).
// ---------------------------------------------------------------------------
__global__ __launch_bounds__(256, 4) void k_hw(const float* __restrict__ x,
                                               const float* __restrict__ W,
                                               const float* __restrict__ a1,
                                               const float* __restrict__ a2,
                                               unsigned short* __restrict__ ht,
                                               float* __restrict__ Etab,
                                               unsigned short* __restrict__ FbfF,
                                               unsigned short* __restrict__ FbfF2) {
  __shared__ float xs[8][256];
  __shared__ unsigned short tile[128][8];   // [f][row]
  const int tid = threadIdx.x;
  const int rowbase = blockIdx.x * 8;

  #pragma unroll
  for (int it = 0; it < 2; ++it) {
    int fi = it * 1024 + tid * 4;
    int r = fi >> 8, k = fi & 255;
    *(f32x4*)&xs[r][k] = *(const f32x4*)(x + (size_t)(rowbase + r) * FIN + k);
  }
  __syncthreads();

  const int r = tid >> 5;    // 0..7
  const int cg = tid & 31;   // cols cg*4..cg*4+3
  f32x4 acc = {0.f, 0.f, 0.f, 0.f};

  #pragma unroll 8
  for (int k = 0; k < FIN; ++k) {
    f32x4 wv = *(const f32x4*)(W + k * FOUT + cg * 4);
    float xv = xs[r][k];
    acc[0] += xv * wv[0];
    acc[1] += xv * wv[1];
    acc[2] += xv * wv[2];
    acc[3] += xv * wv[3];
  }

  #pragma unroll
  for (int c = 0; c < 4; ++c) tile[cg * 4 + c][r] = f2bf(acc[c]);

  // fused s-vectors
  f32x4 av1 = *(const f32x4*)(a1 + cg * 4);
  f32x4 av2 = *(const f32x4*)(a2 + cg * 4);
  float s1 = acc[0] * av1[0] + acc[1] * av1[1] + acc[2] * av1[2] + acc[3] * av1[3];
  float s2 = acc[0] * av2[0] + acc[1] * av2[1] + acc[2] * av2[2] + acc[3] * av2[3];
  #pragma unroll
  for (int off = 16; off > 0; off >>= 1) {
    s1 += __shfl_xor(s1, off, 64);
    s2 += __shfl_xor(s2, off, 64);
  }
  if (cg == 0) {
    const int row = rowbase + r;
    float c0 = s1 + SHIFT;
    float c = fmaxf(c0, SLOPE * c0);
    Etab[(size_t)row * 2]     = __expf(s1 - c);
    Etab[(size_t)row * 2 + 1] = __expf(SLOPE * s1 - c);
    FbfF[row]  = f2bf(__expf(s2));
    FbfF2[row] = f2bf(__expf(SLOPE * s2));
  }
  __syncthreads();

  if (tid < 128) {
    u32x4 v = *(const u32x4*)&tile[tid][0];
    *(u32x4*)(ht + (size_t)tid * NN + rowbase) = v;
  }
}

// ---------------------------------------------------------------------------
// Kernel B: fused masked-softmax aggregation, v11.
// Delta vs v9/v10 (182 us, limiter = per-CU memory-instruction count):
//  * 512 threads x 32 rows/block, 256 blocks (1/CU). 8 waves own 1 f-tile
//    (16 f) x 2 rowgroups -> ht bytes amortize over 2x rows.
//  * ht is NOT staged through LDS: each wave loads its 2 B-fragments/chunk
//    directly from global (dwordx4, register double-buffered one chunk
//    ahead; at 1 block/CU the VGPR budget is effectively unlimited).
//  * per-CU memory instrs per chunk: 42 (R9/R10) -> 9 DMA + 16 vec loads.
//  * R9-proven skeleton kept: full __syncthreads top barrier (drains DMA
//    issued a full iteration earlier), shared af build -> sAF, lgkm-only
//    mid barrier (0xC07F), XOR-swizzled adj staging (0 conflicts),
//    probe MFMAs + ones-MFMA denominator (absmax 0.00195 across R7-R10).
// ---------------------------------------------------------------------------
__global__ __launch_bounds__(512, 1) void k_gat(const int* __restrict__ adj,
                                                const unsigned short* __restrict__ ht,
                                                const float* __restrict__ Etab,
                                                const unsigned short* __restrict__ FbfF,
                                                const unsigned short* __restrict__ FbfF2,
                                                const float* __restrict__ bias,
                                                float* __restrict__ out) {
  __shared__ int sA[2][32 * 64];             // 16 KB: adj, slot s of row r holds group s^(r&15)
  __shared__ unsigned short sF[2][128];      // 512 B: [0,64)=F plane, [64,128)=F2 plane
  __shared__ unsigned short sAF[2][2048];    // 8 KB : A-frags, [rg][k32][lane][8]

  const int tid = threadIdx.x;
  const int wave = tid >> 6;                 // 0..7 = f-tile
  const int lane = tid & 63;
  const int quad = lane >> 4;
  const int m = lane & 15;                   // A-row / B-col label
  const int rowbase = blockIdx.x * 32;

  // ---- runtime layout probes (exact in bf16/fp32) ----
  bf16x8 pm, pinv, pones;
  #pragma unroll
  for (int jj = 0; jj < 8; ++jj) {
    pm[jj] = (__bf16)(float)m;
    pinv[jj] = (__bf16)0.03125f;
    pones[jj] = (__bf16)1.0f;
  }
  f32x4 z = {0.f, 0.f, 0.f, 0.f};
  f32x4 rp = __builtin_amdgcn_mfma_f32_16x16x32_bf16(pm, pinv, z, 0, 0, 0);
  f32x4 cp = __builtin_amdgcn_mfma_f32_16x16x32_bf16(pinv, pm, z, 0, 0, 0);
  int rowmap[4], colmap[4];
  #pragma unroll
  for (int r = 0; r < 4; ++r) {
    rowmap[r] = ((int)(rp[r] + 0.5f)) & 15;
    colmap[r] = ((int)(cp[r] + 0.5f)) & 15;
  }

  // ---- build-phase role: thread t builds 4 weight elements ----
  const int b_half = tid & 1;                 // low/high half of a 8-elem run
  const int b_lane = (tid >> 1) & 63;         // target fragment lane
  const int b_k32  = (tid >> 7) & 1;          // target k32
  const int b_rg   = tid >> 8;                // target rowgroup
  const int b_m    = b_lane & 15;
  const int b_quad = b_lane >> 4;
  const int b_row  = b_rg * 16 + b_m;         // block-local row 0..31
  const int b_jl   = b_k32 * 32 + b_quad * 8 + b_half * 4;  // j-local of elem 0
  const int b_slot = (b_jl >> 2) ^ b_m;       // sA slot holding group jl/4
  const float Eb  = Etab[(size_t)(rowbase + b_row) * 2];
  const float E2b = Etab[(size_t)(rowbase + b_row) * 2 + 1];

  f32x4 acc[2] = {z, z}, den[2] = {z, z};     // [rowgroup]

  // ---- DMA source pointers: wave w stages adj rows 4w..4w+3 ----
  // lane L: r = w*4 + L/16, slot s = L%16 holds group g = s ^ (r&15)
  const int a_r = wave * 4 + (lane >> 4);
  const int a_g = (lane & 15) ^ (a_r & 15);
  const int* srcA = adj + (size_t)(rowbase + a_r) * NN + a_g * 4;
  // F planes: wave 0, lanes 0..15
  const unsigned short* srcF = nullptr;
  if (wave == 0) {
    srcF = (lane < 8) ? (FbfF + lane * 8) : (FbfF2 + (lane - 8) * 8);
  }

  auto stage = [&](int b) {
    async_cp16(&sA[b][wave * 256], srcA);
    srcA += 64;
    if (wave == 0 && lane < 16) {
      async_cp16(&sF[b][0], srcF);
      srcF += 64;
    }
  };

  // ---- B-fragment global source (wave-private, plain vector loads) ----
  const unsigned short* srcB = ht + (size_t)(wave * 16 + m) * NN + quad * 8;

  stage(0);                                      // chunk 0 -> buffer 0
  u32x4 bcur0 = *(const u32x4*)(srcB);           // chunk 0, k32=0
  u32x4 bcur1 = *(const u32x4*)(srcB + 32);      // chunk 0, k32=1

  #pragma unroll 2
  for (int c = 0; c < 128; ++c) {
    const int cs = c & 1, ns = cs ^ 1;

    // Full barrier: drains DMA(c) (issued a full iteration ago) + fences
    // last iteration's sA/sF/sAF reads before overwrite.
    __syncthreads();
    if (c + 1 < 128) stage(ns);                  // DMA(c+1)

    // prefetch next chunk's B-fragments (independent of all barriers)
    u32x4 bnxt0 = bcur0, bnxt1 = bcur1;
    if (c + 1 < 128) {
      bnxt0 = *(const u32x4*)(srcB + (c + 1) * 64);
      bnxt1 = *(const u32x4*)(srcB + (c + 1) * 64 + 32);
    }

    // ---- build phase: 4 weight elements per thread -> sAF[cs] ----
    {
      i32x4 av = *(const i32x4*)&sA[cs][b_row * 64 + b_slot * 4];
      unsigned long long fq = *(const unsigned long long*)&sF[cs][b_jl];
      unsigned long long gq = *(const unsigned long long*)&sF[cs][64 + b_jl];
      unsigned afp0 = 0, afp1 = 0;
      #pragma unroll
      for (int e = 0; e < 4; ++e) {
        const float F = bf2f((unsigned short)(fq >> (16 * e)));
        const float G = bf2f((unsigned short)(gq >> (16 * e)));
        const float w = fmaxf(Eb * F, E2b * G);
        const unsigned wb = av[e] ? (unsigned)f2bf(w) : 0u;
        if (e < 2) afp0 |= wb << (16 * e);
        else       afp1 |= wb << (16 * (e - 2));
      }
      u32x2 pkt; pkt[0] = afp0; pkt[1] = afp1;
      *(u32x2*)&sAF[cs][tid * 4] = pkt;
    }

    // lgkm-only barrier: af writes visible; vmcnt (DMA(c+1) + B-frag
    // prefetch) deliberately NOT drained (0xC07F).
    __builtin_amdgcn_s_waitcnt(0xC07F);
    __builtin_amdgcn_s_barrier();

    // ---- MFMA phase: ds_read af + in-register B-frags ----
    #pragma unroll
    for (int k32 = 0; k32 < 2; ++k32) {
      const bf16x8 bf = __builtin_bit_cast(bf16x8, k32 ? bcur1 : bcur0);
      #pragma unroll
      for (int rg = 0; rg < 2; ++rg) {
        bf16x8 af = __builtin_bit_cast(bf16x8,
            *(const u32x4*)&sAF[cs][rg * 1024 + k32 * 512 + lane * 8]);
        acc[rg] = __builtin_amdgcn_mfma_f32_16x16x32_bf16(af, bf, acc[rg], 0, 0, 0);
        den[rg] = __builtin_amdgcn_mfma_f32_16x16x32_bf16(af, pones, den[rg], 0, 0, 0);
      }
    }

    bcur0 = bnxt0;
    bcur1 = bnxt1;
  }

  // ---- epilogue: wave-private rows x cols, direct store ----
  #pragma unroll
  for (int rg = 0; rg < 2; ++rg) {
    #pragma unroll
    for (int r = 0; r < 4; ++r) {
      const float inv = 1.0f / den[rg][r];
      const int orow = rowbase + rg * 16 + rowmap[r];
      const int col = wave * 16 + colmap[r];
      out[(size_t)orow * FOUT + col] = acc[rg][r] * inv + bias[col];
    }
  }
}

// ---------------------------------------------------------------------------
extern "C" void kernel_launch(void* const* d_in, const int* in_sizes, int n_in,
                              void* d_out, int out_size, void* d_ws, size_t ws_size,
                              hipStream_t stream) {
  const float* x    = (const float*)d_in[0];
  const int*   adj  = (const int*)d_in[1];
  const float* W    = (const float*)d_in[2];
  const float* a1   = (const float*)d_in[3];
  const float* a2   = (const float*)d_in[4];
  const float* bias = (const float*)d_in[5];
  float* out = (float*)d_out;

  char* ws = (char*)d_ws;
  unsigned short* ht = (unsigned short*)ws;                            // 2 MB
  float* Etab = (float*)(ws + (size_t)2 * 1024 * 1024);                // 64 KB
  unsigned short* FbfF =
      (unsigned short*)(ws + (size_t)2 * 1024 * 1024 + 64 * 1024);     // 16 KB
  unsigned short* FbfF2 = FbfF + NN;                                   // 16 KB

  k_hw<<<NN / 8, 256, 0, stream>>>(x, W, a1, a2, ht, Etab, FbfF, FbfF2);
  k_gat<<<NN / 32, 512, 0, stream>>>(adj, ht, Etab, FbfF, FbfF2, bias, out);
}